// Round 9
// baseline (611.021 us; speedup 1.0000x reference)
//
#include <hip/hip_runtime.h>

typedef unsigned short u16;
typedef unsigned int   u32;

typedef __attribute__((ext_vector_type(8))) short bf16x8;
typedef __attribute__((ext_vector_type(4))) float f32x4;

__device__ __forceinline__ u16 f2bf(float f) {
  u32 u = __float_as_uint(f);
  u32 r = (u + 0x7fffu + ((u >> 16) & 1u)) >> 16;
  return (u16)r;
}

__device__ __forceinline__ void async16(const void* g, void* l) {
  __builtin_amdgcn_global_load_lds(
      (const __attribute__((address_space(1))) u32*)g,
      (__attribute__((address_space(3))) u32*)l, 16, 0, 0);
}

// ---------------------------------------------------------------------------
// mega_prep: all pre-conv2 work in ONE launch (unchanged)
// ---------------------------------------------------------------------------
__global__ __launch_bounds__(256) void mega_prep_kern(
    const float* __restrict__ stage5, const float* __restrict__ s6,
    const float* __restrict__ w1,
    const float* __restrict__ g1, const float* __restrict__ b1,
    const float* __restrict__ m1, const float* __restrict__ v1,
    const float* __restrict__ w2, const float* __restrict__ g2,
    const float* __restrict__ b2, const float* __restrict__ m2,
    const float* __restrict__ v2, const float* __restrict__ meta,
    u16* __restrict__ in_bf, u16* __restrict__ w2p,
    u16* __restrict__ clsp, float* __restrict__ clsb,
    float* __restrict__ shift2)
{
  __shared__ __align__(16) char smem[18816];  // max branch: w2 pack 18.4KB
  const int bid = blockIdx.x;
  const int t = threadIdx.x;

  if (bid < 722) {
    // ---- conv1: MFMA GEMM, A=w1 (64x512, scale-folded), B=stage5 pixels ----
    float* sc_s = (float*)smem;           // 64 scales
    float* sh_s = (float*)(smem + 256);   // 64 shifts
    char*  aT   = smem + 512;             // 64x32 bf16 = 4096 B
    char*  bT   = smem + 4608;            // 64x32 bf16 = 4096 B
    const int w = t >> 6, lane = t & 63;
    if (t < 64) {
      float s = g1[t] * rsqrtf(v1[t] + 1e-5f);
      sc_s[t] = s;
      sh_s[t] = b1[t] - m1[t] * s;
    }
    const int m0 = bid * 64;              // 722*64 = 46208 exact, no tail
    const int pS = t & 63, gS = t >> 6;   // staged pixel, k-granule
    const int mS = m0 + pS;
    const int bS = mS / 1444, hwS = mS - bS * 1444;
    const float* s5 = stage5 + (size_t)bS * (512 * 1444) + hwS;
    const int ocA = t >> 2, icqA = t & 3; // A staging: 4 threads/oc-row
    const float* w1r = w1 + (size_t)ocA * 512 + icqA * 8;
    char* aW = aT + (ocA >> 4) * 1024 + (icqA * 16 + (ocA & 15)) * 16;
    char* bW = bT + pS * 64 + ((gS ^ ((pS >> 1) & 3))) * 16;
    const int bR = (w * 16 + (lane & 15)) * 64 +
                   (((lane >> 4) ^ (((lane & 15) >> 1) & 3))) * 16;
    f32x4 acc[4] = {};
    __syncthreads();
    const float sA = sc_s[ocA];
    for (int kc = 0; kc < 16; ++kc) {
      const int ic0 = kc * 32;
      float a8[8], b8[8];
#pragma unroll
      for (int e = 0; e < 8; ++e) a8[e] = w1r[ic0 + e];
#pragma unroll
      for (int e = 0; e < 8; ++e) b8[e] = s5[(size_t)(ic0 + gS * 8 + e) * 1444];
      __syncthreads();   // previous iter's LDS reads complete
      uint4 av, bv;
      av.x = (u32)f2bf(a8[0] * sA) | ((u32)f2bf(a8[1] * sA) << 16);
      av.y = (u32)f2bf(a8[2] * sA) | ((u32)f2bf(a8[3] * sA) << 16);
      av.z = (u32)f2bf(a8[4] * sA) | ((u32)f2bf(a8[5] * sA) << 16);
      av.w = (u32)f2bf(a8[6] * sA) | ((u32)f2bf(a8[7] * sA) << 16);
      bv.x = (u32)f2bf(b8[0]) | ((u32)f2bf(b8[1]) << 16);
      bv.y = (u32)f2bf(b8[2]) | ((u32)f2bf(b8[3]) << 16);
      bv.z = (u32)f2bf(b8[4]) | ((u32)f2bf(b8[5]) << 16);
      bv.w = (u32)f2bf(b8[6]) | ((u32)f2bf(b8[7]) << 16);
      *(uint4*)aW = av;
      *(uint4*)bW = bv;
      __syncthreads();
      bf16x8 bfv = *(const bf16x8*)(bT + bR);
#pragma unroll
      for (int i = 0; i < 4; ++i) {
        bf16x8 af = *(const bf16x8*)(aT + i * 1024 + lane * 16);
        acc[i] = __builtin_amdgcn_mfma_f32_16x16x32_bf16(af, bfv, acc[i], 0, 0, 0);
      }
    }
    const int mE = m0 + w * 16 + (lane & 15);
    const int bE = mE / 1444, hwE = mE - bE * 1444;
    const int h = hwE / 38, wq = hwE - h * 38;
    const int ho = h >> 1, wo = wq >> 1, q = ((h & 1) << 1) | (wq & 1);
    u16* dst = in_bf + (((size_t)bE * 21 + 1 + ho) * 21 + 1 + wo) * 1280 + q * 64;
    const int lq = lane >> 4;
#pragma unroll
    for (int i = 0; i < 4; ++i) {
      int oc = i * 16 + lq * 4;
      float v0 = acc[i][0] + sh_s[oc + 0]; v0 = v0 > 0.f ? v0 : 0.1f * v0;
      float v1_ = acc[i][1] + sh_s[oc + 1]; v1_ = v1_ > 0.f ? v1_ : 0.1f * v1_;
      float v2_ = acc[i][2] + sh_s[oc + 2]; v2_ = v2_ > 0.f ? v2_ : 0.1f * v2_;
      float v3 = acc[i][3] + sh_s[oc + 3]; v3 = v3 > 0.f ? v3 : 0.1f * v3;
      u32 lo = (u32)f2bf(v0) | ((u32)f2bf(v1_) << 16);
      u32 hi = (u32)f2bf(v2_) | ((u32)f2bf(v3) << 16);
      u32* dp = (u32*)(dst + oc);
      dp[0] = lo; dp[1] = hi;
    }
    return;
  }

  if (bid < 3794) {
    // ---- stage6 NCHW -> in_bf NHWC [256,1280) ----
    u16 (*tile)[66] = (u16(*)[66])smem;   // 64x66 u16 = 8448 B
    const int sub = bid - 722;
    const int jt = sub % 6, ct = (sub / 6) % 16, b = sub / 96;
    const int ij0 = jt * 64, c0 = ct * 64;
    const int col = t & 63, rr = t >> 6;
#pragma unroll
    for (int r = 0; r < 16; ++r) {
      int cl = r * 4 + rr;
      int ij = ij0 + col;
      float v = 0.f;
      if (ij < 361) v = s6[((size_t)b * 1024 + c0 + cl) * 361 + ij];
      tile[cl][col] = f2bf(v);
    }
    __syncthreads();
#pragma unroll
    for (int r = 0; r < 16; ++r) {
      int ijl = r * 4 + rr;
      int ij = ij0 + ijl;
      if (ij < 361) {
        int i = ij / 19, j = ij - i * 19;
        in_bf[(((size_t)b * 21 + 1 + i) * 21 + 1 + j) * 1280 + 256 + c0 + col] =
            tile[col][ijl];
      }
    }
    return;
  }

  if (bid < 5394) {
    // ---- border zero: 32 b x 80 border pixels x 1280 ch, 16B per thread ----
    int gi = (bid - 3794) * 256 + t;      // [0, 409600) exact
    int b = gi / 12800;
    int rem = gi - b * 12800;
    int p = rem / 160, qq = rem - p * 160;
    int row, col;
    if (p < 21)      { row = 0;      col = p; }
    else if (p < 42) { row = 20;     col = p - 21; }
    else if (p < 61) { row = p - 41; col = 0; }
    else             { row = p - 60; col = 20; }
    uint4 z = {0u, 0u, 0u, 0u};
    *(uint4*)(in_bf + (((size_t)b * 21 + row) * 21 + col) * 1280 + qq * 8) = z;
    return;
  }

  if (bid < 5694) {
    // ---- meta -> clsp packed (one uint4 = 8 bf16 per thread) + clsb ----
    int idx = (bid - 5394) * 256 + t;     // [0,76800) = 600cm x 128 octets
    int cm = idx >> 7, a = idx & 127;
    int kc = a >> 2, ksub = a & 3;
    int tile_ = cm >> 7, g = (cm >> 4) & 7, mm = cm & 15;
    const float* srcp = meta + (size_t)cm * 1025 + a * 8;
    uint4 v;
    v.x = (u32)f2bf(srcp[0]) | ((u32)f2bf(srcp[1]) << 16);
    v.y = (u32)f2bf(srcp[2]) | ((u32)f2bf(srcp[3]) << 16);
    v.z = (u32)f2bf(srcp[4]) | ((u32)f2bf(srcp[5]) << 16);
    v.w = (u32)f2bf(srcp[6]) | ((u32)f2bf(srcp[7]) << 16);
    size_t dst = (((size_t)tile_ * 32 + kc) * 8 + g) * 512
                 + (size_t)(ksub * 16 + mm) * 8;
    *(uint4*)(clsp + dst) = v;
    if (idx < 600) clsb[idx] = meta[(size_t)idx * 1025 + 1024];
    if (idx < 1024) {
      float sc = g2[idx] * rsqrtf(v2[idx] + 1e-5f);
      shift2[idx] = b2[idx] - m2[idx] * sc;
    }
    return;
  }

  {
    // ---- w2 -> w2p packed, fat blocks: 8 oc x 128 ic each, BN folded ----
    u16* tile = (u16*)smem;               // 8 x 1170 u16 = 18720 B
    float* sc_s = (float*)(smem + 18720); // 8 floats
    const int sub = bid - 5694;           // [0, 1280)
    const int icb = sub % 10;
    const int oc0 = (sub / 10) * 8;
    if (t < 8) sc_s[t] = g2[oc0 + t] * rsqrtf(v2[oc0 + t] + 1e-5f);
    __syncthreads();
    const float* src = w2 + (size_t)oc0 * 11520 + (size_t)icb * 128 * 9;
#pragma unroll
    for (int r = 0; r < 36; ++r) {        // 9216 = 36*256 exact
      int p = r * 256 + t;
      int oc_l = p / 1152, rem = p - oc_l * 1152;
      int ic_l = rem / 9, khw = rem - ic_l * 9;
      tile[oc_l * 1170 + khw * 130 + ic_l] =
          f2bf(src[(size_t)oc_l * 11520 + rem] * sc_s[oc_l]);
    }
    __syncthreads();
#pragma unroll
    for (int r = 0; r < 5; ++r) {         // 1152 uint4 writes
      int wi = r * 256 + t;
      if (wi < 1152) {
        int oc_l = wi / 144, q = wi - oc_l * 144;
        int khw = q >> 4, c = (q >> 2) & 3, ksub = q & 3;
        int oc = oc0 + oc_l;
        int kt = khw * 40 + icb * 4 + c;
        const u16* s = &tile[oc_l * 1170 + khw * 130 + c * 32 + ksub * 8];
        uint4 v;
        v.x = (u32)s[0] | ((u32)s[1] << 16);
        v.y = (u32)s[2] | ((u32)s[3] << 16);
        v.z = (u32)s[4] | ((u32)s[5] << 16);
        v.w = (u32)s[6] | ((u32)s[7] << 16);
        size_t dst = (((size_t)(oc >> 8) * 360 + kt) * 2 + ((oc & 255) >> 7)) * 4096
                     + (size_t)(((oc >> 4) & 7) * 64 + ksub * 16 + (oc & 15)) * 8;
        *(uint4*)(w2p + dst) = v;
      }
    }
  }
}

// ---------------------------------------------------------------------------
// conv2: implicit GEMM, 256(oc) x 192(m), BK=64, now 4 WAVES (256 thr), wave
// tile 128oc x 96m (2oc x 2m wave grid). Fragment-read traffic -36% vs the
// 8-wave 128x48 tiling (112 vs 176 ds_read_b128 per 64-k per CU): LDS-read-
// bound kernel, so bigger wave tiles = fewer LDS bytes/FLOP. acc[8][6] =
// 192 VGPR -> 1 wave/SIMD, full 512-reg budget (__launch_bounds__(256,1));
// 48 independent accumulators keep the MFMA pipe fed from one wave.
// Same proven R8 schedule (2-deep ring, one s_barrier + one vmcnt(0) per
// 64-k), same A-pack/B-swizzle/staging order (256 thr x 2 rounds = old
// 512 x 1 linear order), same grid 244 + XCD chunking.
// ---------------------------------------------------------------------------
__global__ __launch_bounds__(256, 1) void conv2_gemm_kern(
    const u16* __restrict__ Wp, const u16* __restrict__ Ig,
    const float* __restrict__ shift2, u16* __restrict__ pre)
{
  __shared__ u16 As[2][16384];  // 256oc x 64k per slot (32KB): 2 x 8192 chunks
  __shared__ u16 Bs[2][12288];  // 192m x 64k per slot (24KB): 2 x 6144 chunks
  __shared__ float shft[256];

  const int t = threadIdx.x;
  const int w = t >> 6, lane = t & 63;
  const int wm = w >> 1, wn = w & 1;     // wave tile: 128 oc x 96 m

  // bijective XCD chunking: nwg=244, q=30, r=4
  const int xcd = blockIdx.x & 7, sub8 = blockIdx.x >> 3;
  const int s = (xcd < 4 ? xcd * 31 : 124 + (xcd - 4) * 30) + sub8;
  const int mTile = s >> 2, ocTile = s & 3;
  const int m0 = mTile * 192, oc0 = ocTile * 256;

  // B source pointers: 3 groups of 64 rows, rw = t>>2 in [0,64)
  const int rw = t >> 2;
  const int rpart = ((t & 3) ^ ((t >> 3) & 3)) * 8;
  int mA = m0 + rw;        if (mA > 11551) mA = 11551;   // rows 0..63
  int mB = m0 + 64 + rw;   if (mB > 11551) mB = 11551;   // rows 64..127
  int mC = m0 + 128 + rw;  if (mC > 11551) mC = 11551;   // rows 128..191
  const int bA = mA / 361, ijA = mA - bA * 361;
  const int ohA = ijA / 19, owA = ijA - ohA * 19;
  const int bB = mB / 361, ijB = mB - bB * 361;
  const int ohB = ijB / 19, owB = ijB - ohB * 19;
  const int bC = mC / 361, ijC = mC - bC * 361;
  const int ohC = ijC / 19, owC = ijC - ohC * 19;
  const u16* pIa = Ig + (size_t)((bA * 21 + ohA) * 21 + owA) * 1280 + rpart;
  const u16* pIb = Ig + (size_t)((bB * 21 + ohB) * 21 + owB) * 1280 + rpart;
  const u16* pIc = Ig + (size_t)((bC * 21 + ohC) * 21 + owC) * 1280 + rpart;

  // A source (packed): 64k-tile st lives at st*16384 u16; 256 threads cover
  // 2048 u16 per call -> 8 calls per tile at +c*2048.
  const u16* pW = Wp + (size_t)ocTile * 2949120 + (size_t)t * 8;

  // LDS read offsets (u16 units), within a 32k chunk
  const int aOff = wm * 4096 + lane * 8;
  const int bOff = (wn * 96 + (lane & 15)) * 32 +
                   (((lane >> 4) ^ ((lane >> 1) & 3)) * 8);

  // prologue: stage 64k-tile 0 into slot 0 (14 calls); expose latency once
#pragma unroll
  for (int c = 0; c < 8; ++c)
    async16(pW + c * 2048, &As[0][c * 2048 + t * 8]);
  async16(pIa,      &Bs[0][t * 8]);
  async16(pIb,      &Bs[0][2048 + t * 8]);
  async16(pIc,      &Bs[0][4096 + t * 8]);
  async16(pIa + 32, &Bs[0][6144 + t * 8]);
  async16(pIb + 32, &Bs[0][8192 + t * 8]);
  async16(pIc + 32, &Bs[0][10240 + t * 8]);
  asm volatile("s_waitcnt vmcnt(0)" ::: "memory");
  __builtin_amdgcn_s_barrier();

  // staging walker -> 64k-tile 1: sIo = (kh*21+kw)*1280 + pair*64
  int skh = 0, skw = 0, sp = 1, sIo = 64;

  f32x4 acc[8][6] = {};

  for (int kq = 0; kq < 90; ++kq) {
#pragma unroll
    for (int r = 0; r < 2; ++r) {
      const int kt = kq * 2 + r;
      const int cur = r, nxt = r ^ 1;               // literal ring slots
      const int st = (kt < 179) ? kt + 1 : 179;     // tail: dummy re-stage
      const size_t aSrc = (size_t)st * 16384;

      bf16x8 a0[4], a1[4], bf[6];

      // ======== sub-k 0 (chunk 0) ========
#pragma unroll
      for (int j = 0; j < 6; ++j)
        bf[j] = *(const bf16x8*)&Bs[cur][bOff + j * 512];
#pragma unroll
      for (int i = 0; i < 4; ++i)
        a0[i] = *(const bf16x8*)&As[cur][aOff + i * 512];
      // stage next tile: A chunk0 (4 calls) + B chunk0 (3 calls)
      async16(pW + aSrc,        &As[nxt][t * 8]);
      async16(pW + aSrc + 2048, &As[nxt][2048 + t * 8]);
      async16(pW + aSrc + 4096, &As[nxt][4096 + t * 8]);
      async16(pW + aSrc + 6144, &As[nxt][6144 + t * 8]);
      async16(pIa + sIo, &Bs[nxt][t * 8]);
      async16(pIb + sIo, &Bs[nxt][2048 + t * 8]);
      async16(pIc + sIo, &Bs[nxt][4096 + t * 8]);
#pragma unroll
      for (int i = 0; i < 4; ++i)
        a1[i] = *(const bf16x8*)&As[cur][aOff + 2048 + i * 512];

      asm volatile("s_waitcnt lgkmcnt(4)" ::: "memory");
      __builtin_amdgcn_sched_barrier(0);
      __builtin_amdgcn_s_setprio(1);
#pragma unroll
      for (int i = 0; i < 4; ++i)
#pragma unroll
        for (int j = 0; j < 6; ++j)
          acc[i][j] = __builtin_amdgcn_mfma_f32_16x16x32_bf16(
              a0[i], bf[j], acc[i][j], 0, 0, 0);
      __builtin_amdgcn_s_setprio(0);

      asm volatile("s_waitcnt lgkmcnt(0)" ::: "memory");
      __builtin_amdgcn_sched_barrier(0);
      __builtin_amdgcn_s_setprio(1);
#pragma unroll
      for (int i = 0; i < 4; ++i)
#pragma unroll
        for (int j = 0; j < 6; ++j)
          acc[4 + i][j] = __builtin_amdgcn_mfma_f32_16x16x32_bf16(
              a1[i], bf[j], acc[4 + i][j], 0, 0, 0);
      __builtin_amdgcn_s_setprio(0);

      // ======== sub-k 1 (chunk 1) ========
#pragma unroll
      for (int j = 0; j < 6; ++j)
        bf[j] = *(const bf16x8*)&Bs[cur][6144 + bOff + j * 512];
#pragma unroll
      for (int i = 0; i < 4; ++i)
        a0[i] = *(const bf16x8*)&As[cur][8192 + aOff + i * 512];
      // stage next tile: A chunk1 (4 calls) + B chunk1 (3 calls)
      async16(pW + aSrc + 8192,  &As[nxt][8192 + t * 8]);
      async16(pW + aSrc + 10240, &As[nxt][10240 + t * 8]);
      async16(pW + aSrc + 12288, &As[nxt][12288 + t * 8]);
      async16(pW + aSrc + 14336, &As[nxt][14336 + t * 8]);
      async16(pIa + sIo + 32, &Bs[nxt][6144 + t * 8]);
      async16(pIb + sIo + 32, &Bs[nxt][8192 + t * 8]);
      async16(pIc + sIo + 32, &Bs[nxt][10240 + t * 8]);
#pragma unroll
      for (int i = 0; i < 4; ++i)
        a1[i] = *(const bf16x8*)&As[cur][8192 + 2048 + aOff + i * 512];

      asm volatile("s_waitcnt lgkmcnt(4)" ::: "memory");
      __builtin_amdgcn_sched_barrier(0);
      __builtin_amdgcn_s_setprio(1);
#pragma unroll
      for (int i = 0; i < 4; ++i)
#pragma unroll
        for (int j = 0; j < 6; ++j)
          acc[i][j] = __builtin_amdgcn_mfma_f32_16x16x32_bf16(
              a0[i], bf[j], acc[i][j], 0, 0, 0);
      __builtin_amdgcn_s_setprio(0);

      asm volatile("s_waitcnt lgkmcnt(0)" ::: "memory");
      __builtin_amdgcn_sched_barrier(0);
      __builtin_amdgcn_s_setprio(1);
#pragma unroll
      for (int i = 0; i < 4; ++i)
#pragma unroll
        for (int j = 0; j < 6; ++j)
          acc[4 + i][j] = __builtin_amdgcn_mfma_f32_16x16x32_bf16(
              a1[i], bf[j], acc[4 + i][j], 0, 0, 0);
      __builtin_amdgcn_s_setprio(0);

      // ONE counted drain + ONE barrier per 64-k tile
      asm volatile("s_waitcnt vmcnt(0)" ::: "memory");
      __builtin_amdgcn_s_barrier();

      ++sp; sIo += 64;
      if (sp == 20) { sp = 0; ++skw; if (skw == 3) { skw = 0; ++skh; }
                      sIo = (skh * 21 + skw) * 1280; }
    }
  }

  shft[t] = shift2[oc0 + t];
  __syncthreads();   // also drains the tail dummy stages

  const int lq = lane >> 4, lr = lane & 15;
#pragma unroll
  for (int j = 0; j < 6; ++j) {
    const int m = m0 + wn * 96 + j * 16 + lr;
    if (m >= 11552) continue;
    u16* prow = pre + (size_t)m * 1024 + oc0 + wm * 128;
#pragma unroll
    for (int i = 0; i < 8; ++i) {
      const int ocl = i * 16 + lq * 4;
      float v0 = acc[i][j][0] + shft[wm * 128 + ocl + 0]; v0 = v0 > 0.f ? v0 : 0.1f * v0;
      float v1 = acc[i][j][1] + shft[wm * 128 + ocl + 1]; v1 = v1 > 0.f ? v1 : 0.1f * v1;
      float v2 = acc[i][j][2] + shft[wm * 128 + ocl + 2]; v2 = v2 > 0.f ? v2 : 0.1f * v2;
      float v3 = acc[i][j][3] + shft[wm * 128 + ocl + 3]; v3 = v3 > 0.f ? v3 : 0.1f * v3;
      u32 lo = (u32)f2bf(v0) | ((u32)f2bf(v1) << 16);
      u32 hi = (u32)f2bf(v2) | ((u32)f2bf(v3) << 16);
      u32* dp = (u32*)(prow + ocl);
      dp[0] = lo; dp[1] = hi;
    }
  }
}

// ---------------------------------------------------------------------------
// einsum: GEMM A=cls_w packed, B=pre[11552][1024]. 256(m) x 128(cm), 512 thr,
// grid (46,5)=230 -> one round. 3-slot ring, counted vmcnt(3), 1 barrier/iter.
// ---------------------------------------------------------------------------
__global__ __launch_bounds__(512) void einsum_gemm_kern(
    const u16* __restrict__ Ap, const u16* __restrict__ Bg,
    const float* __restrict__ biasg, float* __restrict__ out)
{
  __shared__ u16 Wa[3][4096];   // 128cm x 32k per slot (8KB)
  __shared__ u16 Ib[3][8192];   // 256m x 32k per slot (16KB)
  __shared__ float sbias[128];
  const int t = threadIdx.x;
  const int w = t >> 6, lane = t & 63;
  const int q = w >> 1, ch = w & 1;     // m-quarter, cm-half
  const int m0 = blockIdx.x * 256;
  const int cm0 = blockIdx.y * 128;
  if (t < 128) { int c = cm0 + t; sbias[t] = (c < 600) ? biasg[c] : 0.f; }

  const u16* pA = Ap + (size_t)(cm0 >> 7) * (32 * 4096) + (size_t)t * 8;

  const int rw = t >> 2;
  const int rpart = ((t & 3) ^ ((t >> 3) & 3)) * 8;
  int rB0 = m0 + rw;        if (rB0 > 11551) rB0 = 11551;
  int rB1 = m0 + 128 + rw;  if (rB1 > 11551) rB1 = 11551;
  const u16* pB0 = Bg + (size_t)rB0 * 1024 + rpart;
  const u16* pB1 = Bg + (size_t)rB1 * 1024 + rpart;

  const int aBase = ch * 2048 + lane * 8;            // + i*512
  const int bBase = (q * 64 + (lane & 15)) * 32 +
                    (((lane >> 4) ^ ((lane >> 1) & 3))) * 8;   // + j*512

  // prologue: stage tiles 0 and 1 (6 loads in flight)
#pragma unroll
  for (int st = 0; st < 2; ++st) {
    const size_t off = (size_t)st * 32;
    async16(pA + (size_t)st * 4096, &Wa[st][t * 8]);
    async16(pB0 + off, &Ib[st][t * 8]);
    async16(pB1 + off, &Ib[st][4096 + t * 8]);
  }
  asm volatile("s_waitcnt vmcnt(3)" ::: "memory");   // tile 0 landed
  __builtin_amdgcn_s_barrier();

  f32x4 acc[4][4] = {};

  for (int kt = 0; kt < 32; ++kt) {
    const int cb = kt % 3;
    const int stb = (kt + 2) % 3;                 // slot of tile kt-1: free
    const int st = (kt < 30) ? kt + 2 : 31;       // tail: dummy re-stage
    const size_t off = (size_t)st * 32;
    async16(pA + (size_t)st * 4096, &Wa[stb][t * 8]);
    async16(pB0 + off, &Ib[stb][t * 8]);
    async16(pB1 + off, &Ib[stb][4096 + t * 8]);

    bf16x8 af[4], bfv[4];
#pragma unroll
    for (int i = 0; i < 4; ++i)
      af[i] = *(const bf16x8*)&Wa[cb][aBase + i * 512];
#pragma unroll
    for (int j = 0; j < 4; ++j)
      bfv[j] = *(const bf16x8*)&Ib[cb][bBase + j * 512];
    asm volatile("s_waitcnt lgkmcnt(0)" ::: "memory");
    __builtin_amdgcn_sched_barrier(0);
    __builtin_amdgcn_s_setprio(1);
#pragma unroll
    for (int i = 0; i < 4; ++i)
#pragma unroll
      for (int j = 0; j < 4; ++j)
        acc[i][j] = __builtin_amdgcn_mfma_f32_16x16x32_bf16(
            af[i], bfv[j], acc[i][j], 0, 0, 0);
    __builtin_amdgcn_s_setprio(0);
    // keep tile kt+2's 3 loads in flight; tile kt+1 (oldest 3) drained
    asm volatile("s_waitcnt vmcnt(3)" ::: "memory");
    __builtin_amdgcn_s_barrier();
  }

  const int lq = lane >> 4, lr = lane & 15;
#pragma unroll
  for (int j = 0; j < 4; ++j) {
    int m = m0 + q * 64 + j * 16 + lr;
    if (m >= 11552) continue;
    int b = m / 361, ij = m - b * 361;
    float* obase = out + (size_t)b * 216600 + ij;
#pragma unroll
    for (int i = 0; i < 4; ++i) {
      int cml = ch * 64 + i * 16 + lq * 4;
#pragma unroll
      for (int r = 0; r < 4; ++r) {
        int cm = cm0 + cml + r;
        if (cm < 600) obase[(size_t)cm * 361] = acc[i][j][r] + sbias[cml + r];
      }
    }
  }
}

// ---------------------------------------------------------------------------
// launch: 3 nodes
// ---------------------------------------------------------------------------
extern "C" void kernel_launch(void* const* d_in, const int* in_sizes, int n_in,
                              void* d_out, int out_size, void* d_ws, size_t ws_size,
                              hipStream_t stream)
{
  const float* stage6 = (const float*)d_in[0];
  const float* stage5 = (const float*)d_in[1];
  const float* w1 = (const float*)d_in[2];
  const float* g1 = (const float*)d_in[3];
  const float* b1 = (const float*)d_in[4];
  const float* m1 = (const float*)d_in[5];
  const float* v1 = (const float*)d_in[6];
  const float* w2 = (const float*)d_in[7];
  const float* g2 = (const float*)d_in[8];
  const float* b2 = (const float*)d_in[9];
  const float* m2 = (const float*)d_in[10];
  const float* v2 = (const float*)d_in[11];
  const float* meta = (const float*)d_in[12];
  float* out = (float*)d_out;

  char* ws = (char*)d_ws;
  u16*   in_bf  = (u16*)(ws);                  // 36,126,720 B  (32*21*21*1280 bf16)
  u16*   w2p    = (u16*)(ws + 36126720);       // 23,592,960 B  packed W
  u16*   prebf  = (u16*)(ws + 59719680);       // 23,658,496 B  (11552*1024 bf16)
  u16*   clsp   = (u16*)(ws + 83378176);       //  1,310,720 B  packed cls_w
  float* clsb   = (float*)(ws + 84688896);     //      2,560 B
  float* shift2 = (float*)(ws + 84691456);     //      4,096 B   total ~84.7 MB

  mega_prep_kern<<<6974, 256, 0, stream>>>(
      stage5, stage6, w1, g1, b1, m1, v1, w2, g2, b2, m2, v2, meta,
      in_bf, w2p, clsp, clsb, shift2);
  conv2_gemm_kern<<<244, 256, 0, stream>>>(w2p, in_bf, shift2, prebf);
  einsum_gemm_kern<<<dim3(46, 5), 512, 0, stream>>>(clsp, prebf, clsb, out);
}

// Round 10
// 517.028 us; speedup vs baseline: 1.1818x; 1.1818x over previous
//
#include <hip/hip_runtime.h>

typedef unsigned short u16;
typedef unsigned int   u32;

typedef __attribute__((ext_vector_type(8))) short bf16x8;
typedef __attribute__((ext_vector_type(4))) float f32x4;

__device__ __forceinline__ u16 f2bf(float f) {
  u32 u = __float_as_uint(f);
  u32 r = (u + 0x7fffu + ((u >> 16) & 1u)) >> 16;
  return (u16)r;
}

__device__ __forceinline__ void async16(const void* g, void* l) {
  __builtin_amdgcn_global_load_lds(
      (const __attribute__((address_space(1))) u32*)g,
      (__attribute__((address_space(3))) u32*)l, 16, 0, 0);
}

// ---------------------------------------------------------------------------
// mega_prep: all pre-conv2 work in ONE launch (unchanged)
// ---------------------------------------------------------------------------
__global__ __launch_bounds__(256) void mega_prep_kern(
    const float* __restrict__ stage5, const float* __restrict__ s6,
    const float* __restrict__ w1,
    const float* __restrict__ g1, const float* __restrict__ b1,
    const float* __restrict__ m1, const float* __restrict__ v1,
    const float* __restrict__ w2, const float* __restrict__ g2,
    const float* __restrict__ b2, const float* __restrict__ m2,
    const float* __restrict__ v2, const float* __restrict__ meta,
    u16* __restrict__ in_bf, u16* __restrict__ w2p,
    u16* __restrict__ clsp, float* __restrict__ clsb,
    float* __restrict__ shift2)
{
  __shared__ __align__(16) char smem[18816];  // max branch: w2 pack 18.4KB
  const int bid = blockIdx.x;
  const int t = threadIdx.x;

  if (bid < 722) {
    // ---- conv1: MFMA GEMM, A=w1 (64x512, scale-folded), B=stage5 pixels ----
    float* sc_s = (float*)smem;           // 64 scales
    float* sh_s = (float*)(smem + 256);   // 64 shifts
    char*  aT   = smem + 512;             // 64x32 bf16 = 4096 B
    char*  bT   = smem + 4608;            // 64x32 bf16 = 4096 B
    const int w = t >> 6, lane = t & 63;
    if (t < 64) {
      float s = g1[t] * rsqrtf(v1[t] + 1e-5f);
      sc_s[t] = s;
      sh_s[t] = b1[t] - m1[t] * s;
    }
    const int m0 = bid * 64;              // 722*64 = 46208 exact, no tail
    const int pS = t & 63, gS = t >> 6;   // staged pixel, k-granule
    const int mS = m0 + pS;
    const int bS = mS / 1444, hwS = mS - bS * 1444;
    const float* s5 = stage5 + (size_t)bS * (512 * 1444) + hwS;
    const int ocA = t >> 2, icqA = t & 3; // A staging: 4 threads/oc-row
    const float* w1r = w1 + (size_t)ocA * 512 + icqA * 8;
    char* aW = aT + (ocA >> 4) * 1024 + (icqA * 16 + (ocA & 15)) * 16;
    char* bW = bT + pS * 64 + ((gS ^ ((pS >> 1) & 3))) * 16;
    const int bR = (w * 16 + (lane & 15)) * 64 +
                   (((lane >> 4) ^ (((lane & 15) >> 1) & 3))) * 16;
    f32x4 acc[4] = {};
    __syncthreads();
    const float sA = sc_s[ocA];
    for (int kc = 0; kc < 16; ++kc) {
      const int ic0 = kc * 32;
      float a8[8], b8[8];
#pragma unroll
      for (int e = 0; e < 8; ++e) a8[e] = w1r[ic0 + e];
#pragma unroll
      for (int e = 0; e < 8; ++e) b8[e] = s5[(size_t)(ic0 + gS * 8 + e) * 1444];
      __syncthreads();   // previous iter's LDS reads complete
      uint4 av, bv;
      av.x = (u32)f2bf(a8[0] * sA) | ((u32)f2bf(a8[1] * sA) << 16);
      av.y = (u32)f2bf(a8[2] * sA) | ((u32)f2bf(a8[3] * sA) << 16);
      av.z = (u32)f2bf(a8[4] * sA) | ((u32)f2bf(a8[5] * sA) << 16);
      av.w = (u32)f2bf(a8[6] * sA) | ((u32)f2bf(a8[7] * sA) << 16);
      bv.x = (u32)f2bf(b8[0]) | ((u32)f2bf(b8[1]) << 16);
      bv.y = (u32)f2bf(b8[2]) | ((u32)f2bf(b8[3]) << 16);
      bv.z = (u32)f2bf(b8[4]) | ((u32)f2bf(b8[5]) << 16);
      bv.w = (u32)f2bf(b8[6]) | ((u32)f2bf(b8[7]) << 16);
      *(uint4*)aW = av;
      *(uint4*)bW = bv;
      __syncthreads();
      bf16x8 bfv = *(const bf16x8*)(bT + bR);
#pragma unroll
      for (int i = 0; i < 4; ++i) {
        bf16x8 af = *(const bf16x8*)(aT + i * 1024 + lane * 16);
        acc[i] = __builtin_amdgcn_mfma_f32_16x16x32_bf16(af, bfv, acc[i], 0, 0, 0);
      }
    }
    const int mE = m0 + w * 16 + (lane & 15);
    const int bE = mE / 1444, hwE = mE - bE * 1444;
    const int h = hwE / 38, wq = hwE - h * 38;
    const int ho = h >> 1, wo = wq >> 1, q = ((h & 1) << 1) | (wq & 1);
    u16* dst = in_bf + (((size_t)bE * 21 + 1 + ho) * 21 + 1 + wo) * 1280 + q * 64;
    const int lq = lane >> 4;
#pragma unroll
    for (int i = 0; i < 4; ++i) {
      int oc = i * 16 + lq * 4;
      float v0 = acc[i][0] + sh_s[oc + 0]; v0 = v0 > 0.f ? v0 : 0.1f * v0;
      float v1_ = acc[i][1] + sh_s[oc + 1]; v1_ = v1_ > 0.f ? v1_ : 0.1f * v1_;
      float v2_ = acc[i][2] + sh_s[oc + 2]; v2_ = v2_ > 0.f ? v2_ : 0.1f * v2_;
      float v3 = acc[i][3] + sh_s[oc + 3]; v3 = v3 > 0.f ? v3 : 0.1f * v3;
      u32 lo = (u32)f2bf(v0) | ((u32)f2bf(v1_) << 16);
      u32 hi = (u32)f2bf(v2_) | ((u32)f2bf(v3) << 16);
      u32* dp = (u32*)(dst + oc);
      dp[0] = lo; dp[1] = hi;
    }
    return;
  }

  if (bid < 3794) {
    // ---- stage6 NCHW -> in_bf NHWC [256,1280) ----
    u16 (*tile)[66] = (u16(*)[66])smem;   // 64x66 u16 = 8448 B
    const int sub = bid - 722;
    const int jt = sub % 6, ct = (sub / 6) % 16, b = sub / 96;
    const int ij0 = jt * 64, c0 = ct * 64;
    const int col = t & 63, rr = t >> 6;
#pragma unroll
    for (int r = 0; r < 16; ++r) {
      int cl = r * 4 + rr;
      int ij = ij0 + col;
      float v = 0.f;
      if (ij < 361) v = s6[((size_t)b * 1024 + c0 + cl) * 361 + ij];
      tile[cl][col] = f2bf(v);
    }
    __syncthreads();
#pragma unroll
    for (int r = 0; r < 16; ++r) {
      int ijl = r * 4 + rr;
      int ij = ij0 + ijl;
      if (ij < 361) {
        int i = ij / 19, j = ij - i * 19;
        in_bf[(((size_t)b * 21 + 1 + i) * 21 + 1 + j) * 1280 + 256 + c0 + col] =
            tile[col][ijl];
      }
    }
    return;
  }

  if (bid < 5394) {
    // ---- border zero: 32 b x 80 border pixels x 1280 ch, 16B per thread ----
    int gi = (bid - 3794) * 256 + t;      // [0, 409600) exact
    int b = gi / 12800;
    int rem = gi - b * 12800;
    int p = rem / 160, qq = rem - p * 160;
    int row, col;
    if (p < 21)      { row = 0;      col = p; }
    else if (p < 42) { row = 20;     col = p - 21; }
    else if (p < 61) { row = p - 41; col = 0; }
    else             { row = p - 60; col = 20; }
    uint4 z = {0u, 0u, 0u, 0u};
    *(uint4*)(in_bf + (((size_t)b * 21 + row) * 21 + col) * 1280 + qq * 8) = z;
    return;
  }

  if (bid < 5694) {
    // ---- meta -> clsp packed (one uint4 = 8 bf16 per thread) + clsb ----
    int idx = (bid - 5394) * 256 + t;     // [0,76800) = 600cm x 128 octets
    int cm = idx >> 7, a = idx & 127;
    int kc = a >> 2, ksub = a & 3;
    int tile_ = cm >> 7, g = (cm >> 4) & 7, mm = cm & 15;
    const float* srcp = meta + (size_t)cm * 1025 + a * 8;
    uint4 v;
    v.x = (u32)f2bf(srcp[0]) | ((u32)f2bf(srcp[1]) << 16);
    v.y = (u32)f2bf(srcp[2]) | ((u32)f2bf(srcp[3]) << 16);
    v.z = (u32)f2bf(srcp[4]) | ((u32)f2bf(srcp[5]) << 16);
    v.w = (u32)f2bf(srcp[6]) | ((u32)f2bf(srcp[7]) << 16);
    size_t dst = (((size_t)tile_ * 32 + kc) * 8 + g) * 512
                 + (size_t)(ksub * 16 + mm) * 8;
    *(uint4*)(clsp + dst) = v;
    if (idx < 600) clsb[idx] = meta[(size_t)idx * 1025 + 1024];
    if (idx < 1024) {
      float sc = g2[idx] * rsqrtf(v2[idx] + 1e-5f);
      shift2[idx] = b2[idx] - m2[idx] * sc;
    }
    return;
  }

  {
    // ---- w2 -> w2p packed, fat blocks: 8 oc x 128 ic each, BN folded ----
    u16* tile = (u16*)smem;               // 8 x 1170 u16 = 18720 B
    float* sc_s = (float*)(smem + 18720); // 8 floats
    const int sub = bid - 5694;           // [0, 1280)
    const int icb = sub % 10;
    const int oc0 = (sub / 10) * 8;
    if (t < 8) sc_s[t] = g2[oc0 + t] * rsqrtf(v2[oc0 + t] + 1e-5f);
    __syncthreads();
    const float* src = w2 + (size_t)oc0 * 11520 + (size_t)icb * 128 * 9;
#pragma unroll
    for (int r = 0; r < 36; ++r) {        // 9216 = 36*256 exact
      int p = r * 256 + t;
      int oc_l = p / 1152, rem = p - oc_l * 1152;
      int ic_l = rem / 9, khw = rem - ic_l * 9;
      tile[oc_l * 1170 + khw * 130 + ic_l] =
          f2bf(src[(size_t)oc_l * 11520 + rem] * sc_s[oc_l]);
    }
    __syncthreads();
#pragma unroll
    for (int r = 0; r < 5; ++r) {         // 1152 uint4 writes
      int wi = r * 256 + t;
      if (wi < 1152) {
        int oc_l = wi / 144, q = wi - oc_l * 144;
        int khw = q >> 4, c = (q >> 2) & 3, ksub = q & 3;
        int oc = oc0 + oc_l;
        int kt = khw * 40 + icb * 4 + c;
        const u16* s = &tile[oc_l * 1170 + khw * 130 + c * 32 + ksub * 8];
        uint4 v;
        v.x = (u32)s[0] | ((u32)s[1] << 16);
        v.y = (u32)s[2] | ((u32)s[3] << 16);
        v.z = (u32)s[4] | ((u32)s[5] << 16);
        v.w = (u32)s[6] | ((u32)s[7] << 16);
        size_t dst = (((size_t)(oc >> 8) * 360 + kt) * 2 + ((oc & 255) >> 7)) * 4096
                     + (size_t)(((oc >> 4) & 7) * 64 + ksub * 16 + (oc & 15)) * 8;
        *(uint4*)(w2p + dst) = v;
      }
    }
  }
}

// ---------------------------------------------------------------------------
// conv2: implicit GEMM, 256(oc) x 192(m), BK=64, 8 waves (2oc x 4m, wave tile
// 128oc x 48m), grid 244 (95% CU, bijective XCD chunking). 2-deep LDS ring
// (113 KiB), 180 iters, ONE s_barrier + ONE vmcnt(0) per 64-k tile; counted
// lgkm(4)/lgkm(0) per sub-k for intra-wave LDS/MFMA overlap. Proven best:
// 260 us, MfmaUtil 47, conflicts 0 (R8). R9's 4-wave/128x96 retile (1 wave/
// SIMD) measured 366 us — no TLP to hide memory waits; do not revisit.
// ---------------------------------------------------------------------------
__global__ __launch_bounds__(512, 2) void conv2_gemm_kern(
    const u16* __restrict__ Wp, const u16* __restrict__ Ig,
    const float* __restrict__ shift2, u16* __restrict__ pre)
{
  __shared__ u16 As[2][16384];  // 256oc x 64k per slot (32KB): 2 x 8192 chunks
  __shared__ u16 Bs[2][12288];  // 192m x 64k per slot (24KB): 2 x 6144 chunks
  __shared__ float shft[256];

  const int t = threadIdx.x;
  const int w = t >> 6, lane = t & 63;
  const int wm = w >> 2, wn = w & 3;     // wave tile: 128 oc x 48 m

  // bijective XCD chunking: nwg=244, q=30, r=4
  const int xcd = blockIdx.x & 7, sub8 = blockIdx.x >> 3;
  const int s = (xcd < 4 ? xcd * 31 : 124 + (xcd - 4) * 30) + sub8;
  const int mTile = s >> 2, ocTile = s & 3;
  const int m0 = mTile * 192, oc0 = ocTile * 256;

  // B source pointers (halo-indexed NHWC, pre-swizzled k-quarter)
  const int rw = t >> 2;
  const int rpart = ((t & 3) ^ ((t >> 3) & 3)) * 8;
  int mA = m0 + rw;        if (mA > 11551) mA = 11551;   // rows 0..127
  int mB = m0 + 128 + rw;  if (mB > 11551) mB = 11551;   // rows 128..191 (w<4)
  const int bA = mA / 361, ijA = mA - bA * 361;
  const int ohA = ijA / 19, owA = ijA - ohA * 19;
  const int bB = mB / 361, ijB = mB - bB * 361;
  const int ohB = ijB / 19, owB = ijB - ohB * 19;
  const u16* pI0 = Ig + (size_t)((bA * 21 + ohA) * 21 + owA) * 1280 + rpart;
  const u16* pI1 = Ig + (size_t)((bB * 21 + ohB) * 21 + owB) * 1280 + rpart;

  // A source (packed): 64k-tile st lives at st*16384 u16 (two 8192 chunks)
  const u16* pW = Wp + (size_t)ocTile * 2949120 + (size_t)t * 8;

  // LDS read offsets (u16 units), within a 32k chunk
  const int aOff = wm * 4096 + lane * 8;
  const int bOff = (wn * 48 + (lane & 15)) * 32 +
                   (((lane >> 4) ^ ((lane >> 1) & 3)) * 8);

  // prologue: stage 64k-tile 0 into slot 0; expose latency once
  async16(pW,                 &As[0][t * 8]);
  async16(pW + 4096,          &As[0][4096 + t * 8]);
  async16(pW + 8192,          &As[0][8192 + t * 8]);
  async16(pW + 12288,         &As[0][12288 + t * 8]);
  async16(pI0,                &Bs[0][t * 8]);
  if (w < 4) async16(pI1,     &Bs[0][4096 + t * 8]);
  async16(pI0 + 32,           &Bs[0][6144 + t * 8]);
  if (w < 4) async16(pI1 + 32,&Bs[0][10240 + t * 8]);
  asm volatile("s_waitcnt vmcnt(0)" ::: "memory");
  __builtin_amdgcn_s_barrier();

  // staging walker -> 64k-tile 1: khw = st/20, pair p = st%20, sIo = base+p*64
  int skh = 0, skw = 0, sp = 1, sIo = 64;

  f32x4 acc[8][3] = {};

  for (int kq = 0; kq < 90; ++kq) {
#pragma unroll
    for (int r = 0; r < 2; ++r) {
      const int kt = kq * 2 + r;
      const int cur = r, nxt = r ^ 1;               // literal ring slots
      const int st = (kt < 179) ? kt + 1 : 179;     // tail: dummy re-stage
      const size_t aSrc = (size_t)st * 16384;

      bf16x8 a0[4], a1[4], bf[3];

      // ======== sub-k 0 (chunk 0) ========
#pragma unroll
      for (int i = 0; i < 4; ++i)
        a0[i] = *(const bf16x8*)&As[cur][aOff + i * 512];
#pragma unroll
      for (int j = 0; j < 3; ++j)
        bf[j] = *(const bf16x8*)&Bs[cur][bOff + j * 512];
      async16(pW + aSrc,        &As[nxt][t * 8]);
      async16(pW + aSrc + 4096, &As[nxt][4096 + t * 8]);
      async16(pI0 + sIo,        &Bs[nxt][t * 8]);
      if (w < 4) async16(pI1 + sIo, &Bs[nxt][4096 + t * 8]);
#pragma unroll
      for (int i = 0; i < 4; ++i)
        a1[i] = *(const bf16x8*)&As[cur][aOff + 2048 + i * 512];

      asm volatile("s_waitcnt lgkmcnt(4)" ::: "memory");
      __builtin_amdgcn_sched_barrier(0);
      __builtin_amdgcn_s_setprio(1);
#pragma unroll
      for (int i = 0; i < 4; ++i)
#pragma unroll
        for (int j = 0; j < 3; ++j)
          acc[i][j] = __builtin_amdgcn_mfma_f32_16x16x32_bf16(
              a0[i], bf[j], acc[i][j], 0, 0, 0);
      __builtin_amdgcn_s_setprio(0);

      asm volatile("s_waitcnt lgkmcnt(0)" ::: "memory");
      __builtin_amdgcn_sched_barrier(0);
      __builtin_amdgcn_s_setprio(1);
#pragma unroll
      for (int i = 0; i < 4; ++i)
#pragma unroll
        for (int j = 0; j < 3; ++j)
          acc[4 + i][j] = __builtin_amdgcn_mfma_f32_16x16x32_bf16(
              a1[i], bf[j], acc[4 + i][j], 0, 0, 0);
      __builtin_amdgcn_s_setprio(0);

      // ======== sub-k 1 (chunk 1) ========
#pragma unroll
      for (int i = 0; i < 4; ++i)
        a0[i] = *(const bf16x8*)&As[cur][8192 + aOff + i * 512];
#pragma unroll
      for (int j = 0; j < 3; ++j)
        bf[j] = *(const bf16x8*)&Bs[cur][6144 + bOff + j * 512];
      async16(pW + aSrc + 8192,  &As[nxt][8192 + t * 8]);
      async16(pW + aSrc + 12288, &As[nxt][12288 + t * 8]);
      async16(pI0 + sIo + 32,    &Bs[nxt][6144 + t * 8]);
      if (w < 4) async16(pI1 + sIo + 32, &Bs[nxt][10240 + t * 8]);
#pragma unroll
      for (int i = 0; i < 4; ++i)
        a1[i] = *(const bf16x8*)&As[cur][8192 + 2048 + aOff + i * 512];

      asm volatile("s_waitcnt lgkmcnt(4)" ::: "memory");
      __builtin_amdgcn_sched_barrier(0);
      __builtin_amdgcn_s_setprio(1);
#pragma unroll
      for (int i = 0; i < 4; ++i)
#pragma unroll
        for (int j = 0; j < 3; ++j)
          acc[i][j] = __builtin_amdgcn_mfma_f32_16x16x32_bf16(
              a0[i], bf[j], acc[i][j], 0, 0, 0);
      __builtin_amdgcn_s_setprio(0);

      asm volatile("s_waitcnt lgkmcnt(0)" ::: "memory");
      __builtin_amdgcn_sched_barrier(0);
      __builtin_amdgcn_s_setprio(1);
#pragma unroll
      for (int i = 0; i < 4; ++i)
#pragma unroll
        for (int j = 0; j < 3; ++j)
          acc[4 + i][j] = __builtin_amdgcn_mfma_f32_16x16x32_bf16(
              a1[i], bf[j], acc[4 + i][j], 0, 0, 0);
      __builtin_amdgcn_s_setprio(0);

      // ONE counted drain + ONE barrier per 64-k tile
      asm volatile("s_waitcnt vmcnt(0)" ::: "memory");
      __builtin_amdgcn_s_barrier();

      ++sp; sIo += 64;
      if (sp == 20) { sp = 0; ++skw; if (skw == 3) { skw = 0; ++skh; }
                      sIo = (skh * 21 + skw) * 1280; }
    }
  }

  if (t < 256) shft[t] = shift2[oc0 + t];
  __syncthreads();   // also drains the tail dummy stages

  const int lq = lane >> 4, lr = lane & 15;
#pragma unroll
  for (int j = 0; j < 3; ++j) {
    const int m = m0 + wn * 48 + j * 16 + lr;
    if (m >= 11552) continue;
    u16* prow = pre + (size_t)m * 1024 + oc0 + wm * 128;
#pragma unroll
    for (int i = 0; i < 8; ++i) {
      const int ocl = i * 16 + lq * 4;
      float v0 = acc[i][j][0] + shft[wm * 128 + ocl + 0]; v0 = v0 > 0.f ? v0 : 0.1f * v0;
      float v1 = acc[i][j][1] + shft[wm * 128 + ocl + 1]; v1 = v1 > 0.f ? v1 : 0.1f * v1;
      float v2 = acc[i][j][2] + shft[wm * 128 + ocl + 2]; v2 = v2 > 0.f ? v2 : 0.1f * v2;
      float v3 = acc[i][j][3] + shft[wm * 128 + ocl + 3]; v3 = v3 > 0.f ? v3 : 0.1f * v3;
      u32 lo = (u32)f2bf(v0) | ((u32)f2bf(v1) << 16);
      u32 hi = (u32)f2bf(v2) | ((u32)f2bf(v3) << 16);
      u32* dp = (u32*)(prow + ocl);
      dp[0] = lo; dp[1] = hi;
    }
  }
}

// ---------------------------------------------------------------------------
// einsum: GEMM A=cls_w packed, B=pre[11552][1024]. 256(m) x 128(cm), 512 thr,
// grid (46,5)=230 -> one round. 3-slot ring, counted vmcnt(3), 1 barrier/iter.
// ---------------------------------------------------------------------------
__global__ __launch_bounds__(512) void einsum_gemm_kern(
    const u16* __restrict__ Ap, const u16* __restrict__ Bg,
    const float* __restrict__ biasg, float* __restrict__ out)
{
  __shared__ u16 Wa[3][4096];   // 128cm x 32k per slot (8KB)
  __shared__ u16 Ib[3][8192];   // 256m x 32k per slot (16KB)
  __shared__ float sbias[128];
  const int t = threadIdx.x;
  const int w = t >> 6, lane = t & 63;
  const int q = w >> 1, ch = w & 1;     // m-quarter, cm-half
  const int m0 = blockIdx.x * 256;
  const int cm0 = blockIdx.y * 128;
  if (t < 128) { int c = cm0 + t; sbias[t] = (c < 600) ? biasg[c] : 0.f; }

  const u16* pA = Ap + (size_t)(cm0 >> 7) * (32 * 4096) + (size_t)t * 8;

  const int rw = t >> 2;
  const int rpart = ((t & 3) ^ ((t >> 3) & 3)) * 8;
  int rB0 = m0 + rw;        if (rB0 > 11551) rB0 = 11551;
  int rB1 = m0 + 128 + rw;  if (rB1 > 11551) rB1 = 11551;
  const u16* pB0 = Bg + (size_t)rB0 * 1024 + rpart;
  const u16* pB1 = Bg + (size_t)rB1 * 1024 + rpart;

  const int aBase = ch * 2048 + lane * 8;            // + i*512
  const int bBase = (q * 64 + (lane & 15)) * 32 +
                    (((lane >> 4) ^ ((lane >> 1) & 3))) * 8;   // + j*512

  // prologue: stage tiles 0 and 1 (6 loads in flight)
#pragma unroll
  for (int st = 0; st < 2; ++st) {
    const size_t off = (size_t)st * 32;
    async16(pA + (size_t)st * 4096, &Wa[st][t * 8]);
    async16(pB0 + off, &Ib[st][t * 8]);
    async16(pB1 + off, &Ib[st][4096 + t * 8]);
  }
  asm volatile("s_waitcnt vmcnt(3)" ::: "memory");   // tile 0 landed
  __builtin_amdgcn_s_barrier();

  f32x4 acc[4][4] = {};

  for (int kt = 0; kt < 32; ++kt) {
    const int cb = kt % 3;
    const int stb = (kt + 2) % 3;                 // slot of tile kt-1: free
    const int st = (kt < 30) ? kt + 2 : 31;       // tail: dummy re-stage
    const size_t off = (size_t)st * 32;
    async16(pA + (size_t)st * 4096, &Wa[stb][t * 8]);
    async16(pB0 + off, &Ib[stb][t * 8]);
    async16(pB1 + off, &Ib[stb][4096 + t * 8]);

    bf16x8 af[4], bfv[4];
#pragma unroll
    for (int i = 0; i < 4; ++i)
      af[i] = *(const bf16x8*)&Wa[cb][aBase + i * 512];
#pragma unroll
    for (int j = 0; j < 4; ++j)
      bfv[j] = *(const bf16x8*)&Ib[cb][bBase + j * 512];
    asm volatile("s_waitcnt lgkmcnt(0)" ::: "memory");
    __builtin_amdgcn_sched_barrier(0);
    __builtin_amdgcn_s_setprio(1);
#pragma unroll
    for (int i = 0; i < 4; ++i)
#pragma unroll
      for (int j = 0; j < 4; ++j)
        acc[i][j] = __builtin_amdgcn_mfma_f32_16x16x32_bf16(
            af[i], bfv[j], acc[i][j], 0, 0, 0);
    __builtin_amdgcn_s_setprio(0);
    // keep tile kt+2's 3 loads in flight; tile kt+1 (oldest 3) drained
    asm volatile("s_waitcnt vmcnt(3)" ::: "memory");
    __builtin_amdgcn_s_barrier();
  }

  const int lq = lane >> 4, lr = lane & 15;
#pragma unroll
  for (int j = 0; j < 4; ++j) {
    int m = m0 + q * 64 + j * 16 + lr;
    if (m >= 11552) continue;
    int b = m / 361, ij = m - b * 361;
    float* obase = out + (size_t)b * 216600 + ij;
#pragma unroll
    for (int i = 0; i < 4; ++i) {
      int cml = ch * 64 + i * 16 + lq * 4;
#pragma unroll
      for (int r = 0; r < 4; ++r) {
        int cm = cm0 + cml + r;
        if (cm < 600) obase[(size_t)cm * 361] = acc[i][j][r] + sbias[cml + r];
      }
    }
  }
}

// ---------------------------------------------------------------------------
// launch: 3 nodes
// ---------------------------------------------------------------------------
extern "C" void kernel_launch(void* const* d_in, const int* in_sizes, int n_in,
                              void* d_out, int out_size, void* d_ws, size_t ws_size,
                              hipStream_t stream)
{
  const float* stage6 = (const float*)d_in[0];
  const float* stage5 = (const float*)d_in[1];
  const float* w1 = (const float*)d_in[2];
  const float* g1 = (const float*)d_in[3];
  const float* b1 = (const float*)d_in[4];
  const float* m1 = (const float*)d_in[5];
  const float* v1 = (const float*)d_in[6];
  const float* w2 = (const float*)d_in[7];
  const float* g2 = (const float*)d_in[8];
  const float* b2 = (const float*)d_in[9];
  const float* m2 = (const float*)d_in[10];
  const float* v2 = (const float*)d_in[11];
  const float* meta = (const float*)d_in[12];
  float* out = (float*)d_out;

  char* ws = (char*)d_ws;
  u16*   in_bf  = (u16*)(ws);                  // 36,126,720 B  (32*21*21*1280 bf16)
  u16*   w2p    = (u16*)(ws + 36126720);       // 23,592,960 B  packed W
  u16*   prebf  = (u16*)(ws + 59719680);       // 23,658,496 B  (11552*1024 bf16)
  u16*   clsp   = (u16*)(ws + 83378176);       //  1,310,720 B  packed cls_w
  float* clsb   = (float*)(ws + 84688896);     //      2,560 B
  float* shift2 = (float*)(ws + 84691456);     //      4,096 B   total ~84.7 MB

  mega_prep_kern<<<6974, 256, 0, stream>>>(
      stage5, stage6, w1, g1, b1, m1, v1, w2, g2, b2, m2, v2, meta,
      in_bf, w2p, clsp, clsb, shift2);
  conv2_gemm_kern<<<244, 512, 0, stream>>>(w2p, in_bf, shift2, prebf);
  einsum_gemm_kern<<<dim3(46, 5), 512, 0, stream>>>(clsp, prebf, clsb, out);
}